// Round 19
// baseline (50.973 us; speedup 1.0000x reference)
//
#include <hip/hip_runtime.h>

// L2-distance causal attention with zero-KV sink.
// B=2, H=16, N=2048, D=64. fp32 in/out, bf16 MFMA internally.
//
// Round 18 = Round 17 (best, 48.0us) with 8 waves/block at 16 q/wave
// (QBLK=128, KVBLK=64, 48 KB LDS unchanged).
//   - Block-tiles per CU halve (8704 vs 16896): half the barriers, counted
//     waits, and staging issues per unit work; LDS-read/VALU/MFMA per query
//     unchanged. 2 blocks/CU x 8 waves = 16 waves/CU resident.
//   - Counted-vmcnt pipeline rescaled: per iter LTB(t+1)=4 + STAGE(t+2)=2
//     VMEM; end wait vmcnt(2) retires STAGE(t+1)+LTB(t+1), leaves STAGE(t+2)
//     in flight across the raw s_barrier. Tail drains vmcnt(0).
//   - No online-softmax machinery (sink pins max; bias folded into V'+tb).
//   - T5 s_setprio around both MFMA clusters (won +1us in R17).
//   - grid (32,16), y reversed so heavy q-blocks dispatch first.
//   - Causal mask spans the last TWO tiles (QBLK = 2 x KVBLK).

#define NQ 2048
#define DH 64
#define NT 32   // KV tiles per sequence (2048/64)

typedef float f32x4 __attribute__((ext_vector_type(4)));
typedef __bf16 bf16x8 __attribute__((ext_vector_type(8)));
typedef unsigned short u16x8 __attribute__((ext_vector_type(8)));

union B8 { u16x8 u; bf16x8 b; };

__device__ __forceinline__ unsigned short f2b(float f) {
  unsigned int x = __builtin_bit_cast(unsigned int, f);
  unsigned int r = x + 0x7fffu + ((x >> 16) & 1u);   // RNE to bf16
  return (unsigned short)(r >> 16);
}
__device__ __forceinline__ float b2f(unsigned short u) {
  unsigned int t = ((unsigned int)u) << 16;
  return __builtin_bit_cast(float, t);
}

// K-slot permutation: slot s (bits c1 c0 g1 g0 r1 r0) holds key (c1 g1 g0 c0 r1 r0).
// Makes QK^T's C-layout scores be exactly the PV B-fragment values (no exchange).
__device__ __forceinline__ int kslot(int a) {
  return (a & 0x23) | ((a & 0x04) << 2) | ((a & 0x18) >> 1);
}

__device__ __forceinline__ void gl_lds16(const void* g, void* l) {
  __builtin_amdgcn_global_load_lds(
      (const __attribute__((address_space(1))) unsigned int*)g,
      (__attribute__((address_space(3))) unsigned int*)l, 16, 0, 0);
}

constexpr float QS = 0.3551784733906239f;   // 2*log2(e)/sqrt(66)
constexpr float BS = 0.17758923669531197f;  // log2(e)/sqrt(66)

// ---------------- kernel 1: build per-tile images ----------------
__global__ __launch_bounds__(256) void build_ws(
    const float* __restrict__ k, const float* __restrict__ v,
    unsigned short* __restrict__ wsK, unsigned short* __restrict__ wsV,
    float* __restrict__ wsB)
{
  const int bh = blockIdx.x;          // 0..31
  const int t  = blockIdx.y;          // 0..31
  const int tid  = threadIdx.x;
  const int wid  = tid >> 6;
  const int lane = tid & 63;
  const size_t bhN = (size_t)bh * NQ;
  const int tile64 = t * 64;
  const size_t tileId = (size_t)bh * NT + t;
  unsigned short* Kt = wsK + tileId * 4096;
  unsigned short* Vt = wsV + tileId * 4096;
  float*          Bt = wsB + tileId * 64;

  __shared__ float sTb[64];   // 2^{b_j} by KEY index (for the V pass)

  // K image (+ tb), slot-permuted, XOR-swizzled — exact LDS byte image.
#pragma unroll
  for (int i = 0; i < 4; i++) {
    int f  = i * 256 + tid;
    int kg = f >> 4, d4 = f & 15;
    int slot = kslot(kg);
    const float4* kp = (const float4*)(k + (bhN + tile64 + kg) * DH);
    float4 kk = kp[d4];
    unsigned short h0 = f2b(kk.x), h1 = f2b(kk.y), h2 = f2b(kk.z), h3 = f2b(kk.w);
    float a0 = b2f(h0), a1 = b2f(h1), a2 = b2f(h2), a3 = b2f(h3);
    float ss = a0*a0 + a1*a1 + a2*a2 + a3*a3;     // |k_bf|^2 partial
    ss += __shfl_xor(ss, 1, 64);
    ss += __shfl_xor(ss, 2, 64);
    ss += __shfl_xor(ss, 4, 64);
    ss += __shfl_xor(ss, 8, 64);
    if (d4 == 0) {
      float tb = __builtin_amdgcn_exp2f(-BS * ss);  // 2^{bias}
      Bt[slot] = tb;       // slot-permuted image for the attend kernel
      sTb[kg]  = tb;       // key-indexed for the V pass below
    }
    unsigned int w0 = (unsigned int)h0 | ((unsigned int)h1 << 16);
    unsigned int w1 = (unsigned int)h2 | ((unsigned int)h3 << 16);
    int idx = slot * 64 + ((d4 * 4) ^ ((slot & 7) << 3));
    uint2 wv; wv.x = w0; wv.y = w1;
    *(uint2*)&Kt[idx] = wv;
  }
  __syncthreads();

  // V'^T image (identity slot order), XOR-swizzled, pre-scaled by 2^{b_j}.
#pragma unroll
  for (int jj = 0; jj < 4; jj++) {
    int kgb = jj * 16 + wid * 4;
    const float* vp = v + (bhN + tile64 + kgb) * DH + lane;
    float x0 = vp[0] * sTb[kgb + 0];
    float x1 = vp[DH] * sTb[kgb + 1];
    float x2 = vp[2 * DH] * sTb[kgb + 2];
    float x3 = vp[3 * DH] * sTb[kgb + 3];
    unsigned int w0 = (unsigned int)f2b(x0) | ((unsigned int)f2b(x1) << 16);
    unsigned int w1 = (unsigned int)f2b(x2) | ((unsigned int)f2b(x3) << 16);
    int idx = lane * 64 + (kgb ^ ((lane & 7) << 3));
    uint2 wv; wv.x = w0; wv.y = w1;
    *(uint2*)&Vt[idx] = wv;
  }
}

// ---------------- kernel 2: counted-vmcnt flash attention, 8 waves ----------------
__global__ __launch_bounds__(512) void attend_l2_flash(
    const float* __restrict__ q,
    const unsigned short* __restrict__ wsK,
    const unsigned short* __restrict__ wsV,
    const float* __restrict__ wsB,
    float* __restrict__ out)
{
  const int bh   = blockIdx.x;
  const int qt2  = (gridDim.y - 1) - blockIdx.y;   // heavy blocks dispatch first
  const int qbase = qt2 * 128;
  const int tid  = threadIdx.x;       // 0..511
  const int wid  = tid >> 6;          // 0..7
  const int lane = tid & 63;
  const int g    = lane >> 4;
  const int qi   = lane & 15;
  const int qg   = qbase + wid * 16 + qi;          // this lane's query row
  const size_t bhN = (size_t)bh * NQ;

  __shared__ __align__(16) unsigned short sK[3][4096];   // 3-deep rotation
  __shared__ __align__(16) unsigned short sV[3][4096];

  // ---- Q fragments (single bf16 pass), hoisted ----
  const float* qrow = q + (bhN + qg) * DH;
  bf16x8 q8[2];
#pragma unroll
  for (int ks = 0; ks < 2; ks++) {
    B8 th;
#pragma unroll
    for (int j = 0; j < 8; j++)
      th.u[j] = f2b(qrow[ks * 32 + g * 8 + j] * QS);
    q8[ks] = th.b;
  }

  f32x4 oacc[4] = { {0,0,0,0}, {0,0,0,0}, {0,0,0,0}, {0,0,0,0} };
  f32x4 l4 = {0, 0, 0, 0};        // packed partial denominator

  const int ntiles = 2 * qt2 + 2;
  const size_t tbase = (size_t)bh * NT;
  const float* TB = wsB + tbase * 64;

  // tb for tile t -> 4 register vectors (per-lane slice, g-dependent)
  auto LTB = [&](int t, f32x4* tb) {
    const float* p = TB + t * 64 + 4 * g;
#pragma unroll
    for (int c = 0; c < 4; c++) tb[c] = *(const f32x4*)(p + 16 * c);
  };
  // stage kv-tile t: 2 gl_lds16 per thread (1 K + 1 V), 512-thread linear DMA
  auto STAGE = [&](unsigned short* bK, unsigned short* bV, int t) {
    const char* Kt = (const char*)(wsK + (tbase + t) * 4096);
    const char* Vt = (const char*)(wsV + (tbase + t) * 4096);
    gl_lds16(Kt + tid * 16, (char*)bK + tid * 16);
    gl_lds16(Vt + tid * 16, (char*)bV + tid * 16);
  };

  unsigned short *kA = sK[0], *kB = sK[1], *kC = sK[2];
  unsigned short *vA = sV[0], *vB = sV[1], *vC = sV[2];
  f32x4 tb_cur[4], tb_nxt[4];

  // prologue: S0 | tb0 | S1 -> vmcnt(2) retires S0+tb0, leaves S1 in flight
  STAGE(kA, vA, 0);
  LTB(0, tb_cur);
  STAGE(kB, vB, 1);   // ntiles >= 2 always
  asm volatile("s_waitcnt vmcnt(2)" ::: "memory");
  __builtin_amdgcn_s_barrier();

  for (int t = 0; t < ntiles; t++) {
    const bool hasN1 = (t + 1 < ntiles);
    const bool hasN2 = (t + 2 < ntiles);
    if (hasN1) LTB(t + 1, tb_nxt);          // 4 VMEM (consumed next iter)
    __builtin_amdgcn_sched_barrier(0);
    if (hasN2) STAGE(kC, vC, t + 2);        // 2 VMEM (in flight across barrier)
    __builtin_amdgcn_sched_barrier(0);

    // ---- QK^T from kA, swapped: S^T = K . Q^T (8 MFMA) ----
    f32x4 sc[4] = { {0,0,0,0}, {0,0,0,0}, {0,0,0,0}, {0,0,0,0} };
    __builtin_amdgcn_s_setprio(1);
#pragma unroll
    for (int c = 0; c < 4; c++) {
#pragma unroll
      for (int ks = 0; ks < 2; ks++) {
        int idx = (16 * c + qi) * 64 + ((ks * 32 + g * 8) ^ ((qi & 7) << 3));
        bf16x8 ak = *(const bf16x8*)&kA[idx];
        sc[c] = __builtin_amdgcn_mfma_f32_16x16x32_bf16(ak, q8[ks], sc[c], 0, 0, 0);
      }
    }
    __builtin_amdgcn_s_setprio(0);

    // ---- causal mask on the last TWO tiles (masked -> exp2 gives 0) ----
    if (t >= ntiles - 2) {
      const int tile64 = t * 64;
#pragma unroll
      for (int c = 0; c < 4; c++)
#pragma unroll
        for (int r = 0; r < 4; r++) {
          int key = tile64 + 32 * (c >> 1) + 8 * g + 4 * (c & 1) + r; // pi(slot)
          if (key > qg) sc[c][r] = -1e30f;
        }
    }

    // ---- weights: p = exp2(s_raw); l += p * tb (no max, no rescale) ----
#pragma unroll
    for (int c = 0; c < 4; c++) {
#pragma unroll
      for (int r = 0; r < 4; r++) sc[c][r] = __builtin_amdgcn_exp2f(sc[c][r]);
#pragma unroll
      for (int r = 0; r < 4; r++) l4[r] = __builtin_fmaf(sc[c][r], tb_cur[c][r], l4[r]);
    }

    // ---- P repack (local by slot-permutation construction) ----
    B8 t0, t1;
#pragma unroll
    for (int j = 0; j < 8; j++) {
      t0.b[j] = (__bf16)sc[(j >> 2)][j & 3];
      t1.b[j] = (__bf16)sc[2 + (j >> 2)][j & 3];
    }

    // ---- PV from vA: O^T += V'^T . P^T (bias folded into V') ----
    __builtin_amdgcn_s_setprio(1);
#pragma unroll
    for (int db = 0; db < 4; db++) {
#pragma unroll
      for (int ks = 0; ks < 2; ks++) {
        int idx = (db * 16 + qi) * 64 + ((ks * 32 + g * 8) ^ ((qi & 7) << 3));
        bf16x8 av = *(const bf16x8*)&vA[idx];
        oacc[db] = __builtin_amdgcn_mfma_f32_16x16x32_bf16(av, (ks ? t1.b : t0.b),
                                                           oacc[db], 0, 0, 0);
      }
    }
    __builtin_amdgcn_s_setprio(0);

    // ---- counted wait: STAGE(t+1)+tb(t+1) done; STAGE(t+2) stays in flight ----
    if (hasN2) asm volatile("s_waitcnt vmcnt(2)" ::: "memory");
    else       asm volatile("s_waitcnt vmcnt(0)" ::: "memory");
    __builtin_amdgcn_s_barrier();

    // rotate buffers + tb
    unsigned short* tk = kA; kA = kB; kB = kC; kC = tk;
    unsigned short* tv = vA; vA = vB; vB = vC; vC = tv;
#pragma unroll
    for (int c = 0; c < 4; c++) tb_cur[c] = tb_nxt[c];
  }

  // ---- epilogue: denom = sum(p*tb) + sink weight 1.0 ----
  float lt = (l4[0] + l4[1]) + (l4[2] + l4[3]);
  lt += __shfl_xor(lt, 16, 64);
  lt += __shfl_xor(lt, 32, 64);
  float denom = lt + 1.0f;
  float inv = 1.0f / denom;
  float* op = out + (bhN + qg) * DH;
#pragma unroll
  for (int db = 0; db < 4; db++) {
    float4 o;
    o.x = oacc[db][0] * inv;
    o.y = oacc[db][1] * inv;
    o.z = oacc[db][2] * inv;
    o.w = oacc[db][3] * inv;
    *(float4*)(op + db * 16 + 4 * g) = o;
  }
}

extern "C" void kernel_launch(void* const* d_in, const int* in_sizes, int n_in,
                              void* d_out, int out_size, void* d_ws, size_t ws_size,
                              hipStream_t stream) {
  (void)in_sizes; (void)n_in; (void)out_size; (void)ws_size;
  const float* q = (const float*)d_in[0];
  const float* k = (const float*)d_in[1];
  const float* v = (const float*)d_in[2];
  float* out = (float*)d_out;

  // ws layout: K images 8 MiB | V images 8 MiB | tb 256 KiB
  char* ws = (char*)d_ws;
  unsigned short* wsK = (unsigned short*)ws;
  unsigned short* wsV = (unsigned short*)(ws + (8u << 20));
  float*          wsB = (float*)(ws + (16u << 20));

  build_ws<<<dim3(32, NT), dim3(256), 0, stream>>>(k, v, wsK, wsV, wsB);
  attend_l2_flash<<<dim3(32, 16), dim3(512), 0, stream>>>(q, wsK, wsV, wsB, out);
}

// Round 20
// 47.944 us; speedup vs baseline: 1.0632x; 1.0632x over previous
//
#include <hip/hip_runtime.h>

// L2-distance causal attention with zero-KV sink.
// B=2, H=16, N=2048, D=64. fp32 in/out, bf16 MFMA internally.
//
// FINAL (= Round 17, best measured: 48.0 us total):
//   - No online-softmax machinery (sink pins max; bias folded into V' and tb).
//   - 3 LDS buffers (48 KB -> 3 blocks/CU), 2-deep staging; per tile ONE raw
//     s_barrier + s_waitcnt vmcnt(4): STAGE(t+2) stays in flight across the
//     barrier (never drain to 0 mid-loop). Tail uses vmcnt(0).
//   - tb (2^bias) in registers, loaded one tile ahead.
//   - T5 s_setprio(1) around both MFMA clusters (+1us, role-diverse blocks).
//   - grid (32,32), y reversed so heavy q-blocks dispatch first.

#define NQ 2048
#define DH 64
#define NT 32   // KV tiles per sequence (2048/64)

typedef float f32x4 __attribute__((ext_vector_type(4)));
typedef __bf16 bf16x8 __attribute__((ext_vector_type(8)));
typedef unsigned short u16x8 __attribute__((ext_vector_type(8)));

union B8 { u16x8 u; bf16x8 b; };

__device__ __forceinline__ unsigned short f2b(float f) {
  unsigned int x = __builtin_bit_cast(unsigned int, f);
  unsigned int r = x + 0x7fffu + ((x >> 16) & 1u);   // RNE to bf16
  return (unsigned short)(r >> 16);
}
__device__ __forceinline__ float b2f(unsigned short u) {
  unsigned int t = ((unsigned int)u) << 16;
  return __builtin_bit_cast(float, t);
}

// K-slot permutation: slot s (bits c1 c0 g1 g0 r1 r0) holds key (c1 g1 g0 c0 r1 r0).
// Makes QK^T's C-layout scores be exactly the PV B-fragment values (no exchange).
__device__ __forceinline__ int kslot(int a) {
  return (a & 0x23) | ((a & 0x04) << 2) | ((a & 0x18) >> 1);
}

__device__ __forceinline__ void gl_lds16(const void* g, void* l) {
  __builtin_amdgcn_global_load_lds(
      (const __attribute__((address_space(1))) unsigned int*)g,
      (__attribute__((address_space(3))) unsigned int*)l, 16, 0, 0);
}

constexpr float QS = 0.3551784733906239f;   // 2*log2(e)/sqrt(66)
constexpr float BS = 0.17758923669531197f;  // log2(e)/sqrt(66)

// ---------------- kernel 1: build per-tile images ----------------
__global__ __launch_bounds__(256) void build_ws(
    const float* __restrict__ k, const float* __restrict__ v,
    unsigned short* __restrict__ wsK, unsigned short* __restrict__ wsV,
    float* __restrict__ wsB)
{
  const int bh = blockIdx.x;          // 0..31
  const int t  = blockIdx.y;          // 0..31
  const int tid  = threadIdx.x;
  const int wid  = tid >> 6;
  const int lane = tid & 63;
  const size_t bhN = (size_t)bh * NQ;
  const int tile64 = t * 64;
  const size_t tileId = (size_t)bh * NT + t;
  unsigned short* Kt = wsK + tileId * 4096;
  unsigned short* Vt = wsV + tileId * 4096;
  float*          Bt = wsB + tileId * 64;

  __shared__ float sTb[64];   // 2^{b_j} by KEY index (for the V pass)

  // K image (+ tb), slot-permuted, XOR-swizzled — exact LDS byte image.
#pragma unroll
  for (int i = 0; i < 4; i++) {
    int f  = i * 256 + tid;
    int kg = f >> 4, d4 = f & 15;
    int slot = kslot(kg);
    const float4* kp = (const float4*)(k + (bhN + tile64 + kg) * DH);
    float4 kk = kp[d4];
    unsigned short h0 = f2b(kk.x), h1 = f2b(kk.y), h2 = f2b(kk.z), h3 = f2b(kk.w);
    float a0 = b2f(h0), a1 = b2f(h1), a2 = b2f(h2), a3 = b2f(h3);
    float ss = a0*a0 + a1*a1 + a2*a2 + a3*a3;     // |k_bf|^2 partial
    ss += __shfl_xor(ss, 1, 64);
    ss += __shfl_xor(ss, 2, 64);
    ss += __shfl_xor(ss, 4, 64);
    ss += __shfl_xor(ss, 8, 64);
    if (d4 == 0) {
      float tb = __builtin_amdgcn_exp2f(-BS * ss);  // 2^{bias}
      Bt[slot] = tb;       // slot-permuted image for the attend kernel
      sTb[kg]  = tb;       // key-indexed for the V pass below
    }
    unsigned int w0 = (unsigned int)h0 | ((unsigned int)h1 << 16);
    unsigned int w1 = (unsigned int)h2 | ((unsigned int)h3 << 16);
    int idx = slot * 64 + ((d4 * 4) ^ ((slot & 7) << 3));
    uint2 wv; wv.x = w0; wv.y = w1;
    *(uint2*)&Kt[idx] = wv;
  }
  __syncthreads();

  // V'^T image (identity slot order), XOR-swizzled, pre-scaled by 2^{b_j}.
#pragma unroll
  for (int jj = 0; jj < 4; jj++) {
    int kgb = jj * 16 + wid * 4;
    const float* vp = v + (bhN + tile64 + kgb) * DH + lane;
    float x0 = vp[0] * sTb[kgb + 0];
    float x1 = vp[DH] * sTb[kgb + 1];
    float x2 = vp[2 * DH] * sTb[kgb + 2];
    float x3 = vp[3 * DH] * sTb[kgb + 3];
    unsigned int w0 = (unsigned int)f2b(x0) | ((unsigned int)f2b(x1) << 16);
    unsigned int w1 = (unsigned int)f2b(x2) | ((unsigned int)f2b(x3) << 16);
    int idx = lane * 64 + (kgb ^ ((lane & 7) << 3));
    uint2 wv; wv.x = w0; wv.y = w1;
    *(uint2*)&Vt[idx] = wv;
  }
}

// ---------------- kernel 2: counted-vmcnt flash attention ----------------
__global__ __launch_bounds__(256) void attend_l2_flash(
    const float* __restrict__ q,
    const unsigned short* __restrict__ wsK,
    const unsigned short* __restrict__ wsV,
    const float* __restrict__ wsB,
    float* __restrict__ out)
{
  const int bh   = blockIdx.x;
  const int qt   = (gridDim.y - 1) - blockIdx.y;   // heavy tiles dispatch first
  const int qbase = qt * 64;
  const int tid  = threadIdx.x;
  const int wid  = tid >> 6;
  const int lane = tid & 63;
  const int g    = lane >> 4;
  const int qi   = lane & 15;
  const int qg   = qbase + wid * 16 + qi;          // this lane's query row
  const size_t bhN = (size_t)bh * NQ;

  __shared__ __align__(16) unsigned short sK[3][4096];   // 3-deep rotation
  __shared__ __align__(16) unsigned short sV[3][4096];

  // ---- Q fragments (single bf16 pass), hoisted ----
  const float* qrow = q + (bhN + qg) * DH;
  bf16x8 q8[2];
#pragma unroll
  for (int ks = 0; ks < 2; ks++) {
    B8 th;
#pragma unroll
    for (int j = 0; j < 8; j++)
      th.u[j] = f2b(qrow[ks * 32 + g * 8 + j] * QS);
    q8[ks] = th.b;
  }

  f32x4 oacc[4] = { {0,0,0,0}, {0,0,0,0}, {0,0,0,0}, {0,0,0,0} };
  f32x4 l4 = {0, 0, 0, 0};        // packed partial denominator

  const int ntiles = qt + 1;
  const size_t tbase = (size_t)bh * NT;
  const float* TB = wsB + tbase * 64;

  // tb for tile t -> 4 register vectors (per-lane slice, g-dependent)
  auto LTB = [&](int t, f32x4* tb) {
    const float* p = TB + t * 64 + 4 * g;
#pragma unroll
    for (int c = 0; c < 4; c++) tb[c] = *(const f32x4*)(p + 16 * c);
  };
  // stage kv-tile t: 4 gl_lds16 per thread (2 K + 2 V), linear DMA
  auto STAGE = [&](unsigned short* bK, unsigned short* bV, int t) {
    const char* Kt = (const char*)(wsK + (tbase + t) * 4096);
    const char* Vt = (const char*)(wsV + (tbase + t) * 4096);
#pragma unroll
    for (int c = 0; c < 2; c++) {
      int boff = wid * 2048 + c * 1024;
      gl_lds16(Kt + boff + lane * 16, (char*)bK + boff);
      gl_lds16(Vt + boff + lane * 16, (char*)bV + boff);
    }
  };

  unsigned short *kA = sK[0], *kB = sK[1], *kC = sK[2];
  unsigned short *vA = sV[0], *vB = sV[1], *vC = sV[2];
  f32x4 tb_cur[4], tb_nxt[4];

  // prologue: S0 | tb0 | S1  -> vmcnt(4) leaves S1 in flight, S0+tb0 done
  STAGE(kA, vA, 0);
  LTB(0, tb_cur);
  if (ntiles > 1) {
    STAGE(kB, vB, 1);
    asm volatile("s_waitcnt vmcnt(4)" ::: "memory");
  } else {
    asm volatile("s_waitcnt vmcnt(0)" ::: "memory");
  }
  __builtin_amdgcn_s_barrier();

  for (int t = 0; t < ntiles; t++) {
    const bool hasN1 = (t + 1 < ntiles);
    const bool hasN2 = (t + 2 < ntiles);
    if (hasN1) LTB(t + 1, tb_nxt);          // 4 VMEM (consumed next iter)
    __builtin_amdgcn_sched_barrier(0);
    if (hasN2) STAGE(kC, vC, t + 2);        // 4 VMEM (in flight across barrier)
    __builtin_amdgcn_sched_barrier(0);

    // ---- QK^T from kA, swapped: S^T = K . Q^T (8 MFMA) ----
    f32x4 sc[4] = { {0,0,0,0}, {0,0,0,0}, {0,0,0,0}, {0,0,0,0} };
    __builtin_amdgcn_s_setprio(1);
#pragma unroll
    for (int c = 0; c < 4; c++) {
#pragma unroll
      for (int ks = 0; ks < 2; ks++) {
        int idx = (16 * c + qi) * 64 + ((ks * 32 + g * 8) ^ ((qi & 7) << 3));
        bf16x8 ak = *(const bf16x8*)&kA[idx];
        sc[c] = __builtin_amdgcn_mfma_f32_16x16x32_bf16(ak, q8[ks], sc[c], 0, 0, 0);
      }
    }
    __builtin_amdgcn_s_setprio(0);

    // ---- causal mask on diag tile (masked -> exp2 gives exactly 0) ----
    if (t == ntiles - 1) {
      const int tile64 = t * 64;
#pragma unroll
      for (int c = 0; c < 4; c++)
#pragma unroll
        for (int r = 0; r < 4; r++) {
          int key = tile64 + 32 * (c >> 1) + 8 * g + 4 * (c & 1) + r; // pi(slot)
          if (key > qg) sc[c][r] = -1e30f;
        }
    }

    // ---- weights: p = exp2(s_raw); l += p * tb (no max, no rescale) ----
#pragma unroll
    for (int c = 0; c < 4; c++) {
#pragma unroll
      for (int r = 0; r < 4; r++) sc[c][r] = __builtin_amdgcn_exp2f(sc[c][r]);
#pragma unroll
      for (int r = 0; r < 4; r++) l4[r] = __builtin_fmaf(sc[c][r], tb_cur[c][r], l4[r]);
    }

    // ---- P repack (local by slot-permutation construction) ----
    B8 t0, t1;
#pragma unroll
    for (int j = 0; j < 8; j++) {
      t0.b[j] = (__bf16)sc[(j >> 2)][j & 3];
      t1.b[j] = (__bf16)sc[2 + (j >> 2)][j & 3];
    }

    // ---- PV from vA: O^T += V'^T . P^T (bias folded into V') ----
    __builtin_amdgcn_s_setprio(1);
#pragma unroll
    for (int db = 0; db < 4; db++) {
#pragma unroll
      for (int ks = 0; ks < 2; ks++) {
        int idx = (db * 16 + qi) * 64 + ((ks * 32 + g * 8) ^ ((qi & 7) << 3));
        bf16x8 av = *(const bf16x8*)&vA[idx];
        oacc[db] = __builtin_amdgcn_mfma_f32_16x16x32_bf16(av, (ks ? t1.b : t0.b),
                                                           oacc[db], 0, 0, 0);
      }
    }
    __builtin_amdgcn_s_setprio(0);

    // ---- counted wait: STAGE(t+1)+tb(t+1) done; STAGE(t+2) stays in flight ----
    if (hasN2) asm volatile("s_waitcnt vmcnt(4)" ::: "memory");
    else       asm volatile("s_waitcnt vmcnt(0)" ::: "memory");
    __builtin_amdgcn_s_barrier();

    // rotate buffers + tb
    unsigned short* tk = kA; kA = kB; kB = kC; kC = tk;
    unsigned short* tv = vA; vA = vB; vB = vC; vC = tv;
#pragma unroll
    for (int c = 0; c < 4; c++) tb_cur[c] = tb_nxt[c];
  }

  // ---- epilogue: denom = sum(p*tb) + sink weight 1.0 ----
  float lt = (l4[0] + l4[1]) + (l4[2] + l4[3]);
  lt += __shfl_xor(lt, 16, 64);
  lt += __shfl_xor(lt, 32, 64);
  float denom = lt + 1.0f;
  float inv = 1.0f / denom;
  float* op = out + (bhN + qg) * DH;
#pragma unroll
  for (int db = 0; db < 4; db++) {
    float4 o;
    o.x = oacc[db][0] * inv;
    o.y = oacc[db][1] * inv;
    o.z = oacc[db][2] * inv;
    o.w = oacc[db][3] * inv;
    *(float4*)(op + db * 16 + 4 * g) = o;
  }
}

extern "C" void kernel_launch(void* const* d_in, const int* in_sizes, int n_in,
                              void* d_out, int out_size, void* d_ws, size_t ws_size,
                              hipStream_t stream) {
  (void)in_sizes; (void)n_in; (void)out_size; (void)ws_size;
  const float* q = (const float*)d_in[0];
  const float* k = (const float*)d_in[1];
  const float* v = (const float*)d_in[2];
  float* out = (float*)d_out;

  // ws layout: K images 8 MiB | V images 8 MiB | tb 256 KiB
  char* ws = (char*)d_ws;
  unsigned short* wsK = (unsigned short*)ws;
  unsigned short* wsV = (unsigned short*)(ws + (8u << 20));
  float*          wsB = (float*)(ws + (16u << 20));

  build_ws<<<dim3(32, NT), dim3(256), 0, stream>>>(k, v, wsK, wsV, wsB);
  attend_l2_flash<<<dim3(32, NT), dim3(256), 0, stream>>>(q, wsK, wsV, wsB, out);
}